// Round 1
// baseline (209.054 us; speedup 1.0000x reference)
//
#include <hip/hip_runtime.h>
#include <hip/hip_bf16.h>

// GRUCell (B=262144, IN=2, H=50) + critic + actor-softmax.
// Inputs fp32, outputs fp32: d_out = h_new[B,50] | c[B,1] | pi[B,2].
// Extended-K MFMA: x[64]=[h(50),s(2),1,0...], W[64]=[w_hh,w_ih,bias,0...].
// R8 = R7 with BDIM 256 -> 1024. wlds (24.5KB of weight fragments) is
// identical in every block; at BDIM=256 it was duplicated 4x per CU and
// capped occupancy at 16 waves/CU (LDS-limited). With 16 waves/block the
// per-block LDS is 61440B -> 2 blocks/CU -> 32 waves/CU (100% cap).
// Kernel remains barrier-free after init: each wave owns a private
// 16-row band of the 256-row block tile.

#define BDIM 1024

typedef __bf16 bf16x8 __attribute__((ext_vector_type(8)));
typedef float f32x4 __attribute__((ext_vector_type(4)));
typedef unsigned __attribute__((may_alias)) u32a;
typedef unsigned short __attribute__((may_alias)) u16a;

__device__ __forceinline__ float bf2f(unsigned short u) {
    union { unsigned u; float f; } x; x.u = ((unsigned)u) << 16; return x.f;
}
__device__ __forceinline__ unsigned short f2bf(float f) {   // init path only
    union { float f; unsigned u; } x; x.f = f;
    unsigned r = x.u + 0x7fffu + ((x.u >> 16) & 1u);
    return (unsigned short)(r >> 16);
}
__device__ __forceinline__ unsigned packbf(float a, float b) {  // v_cvt_pk_bf16_f32
    union { __hip_bfloat162 h; unsigned u; } c;
    c.h = __float22bfloat162_rn(make_float2(a, b));
    return c.u;
}
__device__ __forceinline__ bf16x8 ldsfrag(const unsigned short* p) {
    bf16x8 v; __builtin_memcpy(&v, p, 16); return v;   // alias-safe b128 read
}

__global__ __launch_bounds__(BDIM, 8) void gru_fused(
    const float* __restrict__ s,
    const float* __restrict__ h,
    const float* __restrict__ w_ih,
    const float* __restrict__ w_hh,
    const float* __restrict__ b_ih,
    const float* __restrict__ b_hh,
    const float* __restrict__ actor_w,
    const float* __restrict__ actor_b,
    const float* __restrict__ critic_w,
    const float* __restrict__ critic_b,
    float* __restrict__ out,
    int Btot, int nTiles)
{
    // bf16 x-tile: 256 rows x 72 shorts (144B stride); shorts 0..49 h, 50..51 s,
    // 52 = 1.0, 53..63 = 0 (constants written once at init), 64..71 pad.
    __shared__ __align__(16) unsigned short xlds[256 * 72];
    // weight B-fragments: [g(3)][t(4)][ks(2)][lane(64)][8 bf16] — block-shared
    __shared__ __align__(16) unsigned short wlds[1536 * 8];

    const int tid  = threadIdx.x;
    const int wave = tid >> 6;           // 0..15
    const int lane = tid & 63;
    const int c16  = lane & 15;
    const int quad = lane >> 4;
    const int R    = wave * 16;          // this wave's private 16-row band

    u32a* xlds32 = (u32a*)xlds;

    // ---- init: constant zone of xlds (one pass, race-free) ----
    for (int i = tid; i < 256 * 36; i += BDIM)
        xlds32[i] = ((i % 36) == 26) ? 0x00003f80u : 0u;   // k=52 -> 1.0 bf16

    // ---- init: swizzled bf16 weight fragments into wlds ----
    for (int e = tid; e < 1536; e += BDIM) {
        int ln = e & 63;
        int ks = (e >> 6) & 1;
        int t  = (e >> 7) & 3;
        int g  = e >> 9;
        int n  = t * 16 + (ln & 15);
        int kbase = ks * 32 + (ln >> 4) * 8;
        unsigned short vals[8];
        if (n < 50) {
            int r = g * 50 + n;
            #pragma unroll
            for (int i = 0; i < 8; ++i) {
                int k = kbase + i;
                float v = 0.f;
                if (k < 50)       v = w_hh[r * 50 + k];
                else if (k == 50) v = (g < 2) ? w_ih[r * 2 + 0] : 0.f;
                else if (k == 51) v = (g < 2) ? w_ih[r * 2 + 1] : 0.f;
                else if (k == 52) {
                    v = b_hh[r];                 // n-gate: b_hh only
                    if (g < 2) v += b_ih[r];     // r/z: both biases fused
                }
                vals[i] = f2bf(v);
            }
        } else {
            #pragma unroll
            for (int i = 0; i < 8; ++i) vals[i] = 0;
        }
        #pragma unroll
        for (int i = 0; i < 8; ++i) wlds[e * 8 + i] = vals[i];
    }

    // ---- hoisted per-lane constants (loop-invariant global reads) ----
    float wi0[4], wi1[4], bi[4], aw0[4], aw1[4], awc[4];
    #pragma unroll
    for (int t = 0; t < 4; ++t) {
        int j = t * 16 + c16;
        bool ok = (j < 50);
        wi0[t] = ok ? w_ih[(100 + j) * 2 + 0] : 0.f;
        wi1[t] = ok ? w_ih[(100 + j) * 2 + 1] : 0.f;
        bi[t]  = ok ? b_ih[100 + j]           : 0.f;
        aw0[t] = ok ? actor_w[j]              : 0.f;
        aw1[t] = ok ? actor_w[50 + j]         : 0.f;
        awc[t] = ok ? critic_w[j]             : 0.f;
    }
    const float ab0 = actor_b[0], ab1 = actor_b[1], cb = critic_b[0];

    __syncthreads();   // the ONLY barrier: wlds + xlds const zone visible

    const float2* h2 = (const float2*)h;
    const float2* s2 = (const float2*)s;
    const long long outc = (long long)Btot * 50;
    float2* opi = (float2*)(out + (long long)Btot * 51);

    // ---- prefetch first tile (this wave's 16 rows: 400 h-float2 + 16 s) ----
    float2 pf[7];
    int bt = blockIdx.x;
    {
        long long hb = (long long)(bt * 256 + R) * 25;
        #pragma unroll
        for (int j = 0; j < 6; ++j) pf[j] = h2[hb + lane + j * 64];
        if (lane < 16)      pf[6] = h2[hb + 384 + lane];
        else if (lane < 32) pf[6] = s2[bt * 256 + R + lane - 16];
    }

    while (bt < nTiles) {
        const int rowbase = bt * 256;

        // ---- stage own band: regs -> LDS (alias-safe u32a writes) ----
        #pragma unroll
        for (int j = 0; j < 6; ++j) {
            int d = lane + j * 64;
            int r = d / 25, dk = d - r * 25;
            xlds32[(R + r) * 36 + dk] = packbf(pf[j].x, pf[j].y);
        }
        if (lane < 16)
            xlds32[(R + 15) * 36 + 9 + lane] = packbf(pf[6].x, pf[6].y);
        else if (lane < 32)
            xlds32[(R + lane - 16) * 36 + 25] = packbf(pf[6].x, pf[6].y);

        // compiler fence: staging writes ordered before all following reads
        asm volatile("" ::: "memory");

        // ---- issue next tile's loads (latency hidden by compute) ----
        const int nbt = bt + gridDim.x;
        {
            int pb = (nbt < nTiles) ? nbt : bt;
            long long hb = (long long)(pb * 256 + R) * 25;
            #pragma unroll
            for (int j = 0; j < 6; ++j) pf[j] = h2[hb + lane + j * 64];
            if (lane < 16)      pf[6] = h2[hb + 384 + lane];
            else if (lane < 32) pf[6] = s2[pb * 256 + R + lane - 16];
        }

        // ---- s rows for gate math (L2-hot, 16-lane broadcast) ----
        float2 srow[4];
        #pragma unroll
        for (int reg = 0; reg < 4; ++reg)
            srow[reg] = s2[rowbase + R + quad * 4 + reg];

        // ---- A fragments (own band, alias-safe reads) ----
        const unsigned short* arow = &xlds[(R + c16) * 72 + quad * 8];
        bf16x8 a0 = ldsfrag(arow);        // k 0..31
        bf16x8 a1 = ldsfrag(arow + 32);   // k 32..63

        // ---- per-t: 6 MFMAs then gate math ----
        float hn_r[4][4];
        #pragma unroll
        for (int t = 0; t < 4; ++t) {
            f32x4 ar = {0.f,0.f,0.f,0.f}, az = ar, an = ar;
            const int tb = (t * 128 + lane) * 8;   // shorts; ks +512, g +4096
            bf16x8 br0 = ldsfrag(&wlds[tb]);
            bf16x8 br1 = ldsfrag(&wlds[tb + 512]);
            bf16x8 bz0 = ldsfrag(&wlds[tb + 4096]);
            bf16x8 bz1 = ldsfrag(&wlds[tb + 4608]);
            bf16x8 bn0 = ldsfrag(&wlds[tb + 8192]);
            bf16x8 bn1 = ldsfrag(&wlds[tb + 8704]);
            ar = __builtin_amdgcn_mfma_f32_16x16x32_bf16(a0, br0, ar, 0, 0, 0);
            ar = __builtin_amdgcn_mfma_f32_16x16x32_bf16(a1, br1, ar, 0, 0, 0);
            az = __builtin_amdgcn_mfma_f32_16x16x32_bf16(a0, bz0, az, 0, 0, 0);
            az = __builtin_amdgcn_mfma_f32_16x16x32_bf16(a1, bz1, az, 0, 0, 0);
            an = __builtin_amdgcn_mfma_f32_16x16x32_bf16(a0, bn0, an, 0, 0, 0);
            an = __builtin_amdgcn_mfma_f32_16x16x32_bf16(a1, bn1, an, 0, 0, 0);

            int j = t * 16 + c16;
            #pragma unroll
            for (int reg = 0; reg < 4; ++reg) {
                int lr = R + quad * 4 + reg;       // C/D: row = quad*4+reg
                float inn = fmaf(srow[reg].y, wi1[t],
                            fmaf(srow[reg].x, wi0[t], bi[t]));
                float rg = __builtin_amdgcn_rcpf(1.f + __expf(-ar[reg]));
                float zg = __builtin_amdgcn_rcpf(1.f + __expf(-az[reg]));
                float x = inn + rg * an[reg];
                x = fminf(fmaxf(x, -20.f), 20.f);
                float e2 = __expf(2.f * x);
                float ng = (e2 - 1.f) * __builtin_amdgcn_rcpf(e2 + 1.f);
                float hv = bf2f(((const u16a*)xlds)[lr * 72 + j]);
                float hnew = (1.f - zg) * ng + zg * hv;
                bool ok = (j < 50);
                hn_r[reg][t] = ok ? hnew : 0.f;
                if (ok) out[(long long)(rowbase + lr) * 50 + j] = hnew;
            }
        }

        // ---- heads from registers: 16-lane shfl_xor butterfly per row ----
        float sum0[4], sum1[4], sumc[4];
        #pragma unroll
        for (int reg = 0; reg < 4; ++reg) {
            float p0 = 0.f, p1 = 0.f, pc = 0.f;
            #pragma unroll
            for (int t = 0; t < 4; ++t) {
                p0 = fmaf(hn_r[reg][t], aw0[t], p0);
                p1 = fmaf(hn_r[reg][t], aw1[t], p1);
                pc = fmaf(hn_r[reg][t], awc[t], pc);
            }
            #pragma unroll
            for (int m = 1; m < 16; m <<= 1) {
                p0 += __shfl_xor(p0, m);
                p1 += __shfl_xor(p1, m);
                pc += __shfl_xor(pc, m);
            }
            sum0[reg] = p0; sum1[reg] = p1; sumc[reg] = pc;
        }
        if (c16 < 4) {   // lane c16==reg writes row quad*4+c16
            float A0 = (c16 == 0) ? sum0[0] : (c16 == 1) ? sum0[1]
                     : (c16 == 2) ? sum0[2] : sum0[3];
            float A1 = (c16 == 0) ? sum1[0] : (c16 == 1) ? sum1[1]
                     : (c16 == 2) ? sum1[2] : sum1[3];
            float C  = (c16 == 0) ? sumc[0] : (c16 == 1) ? sumc[1]
                     : (c16 == 2) ? sumc[2] : sumc[3];
            int gr = rowbase + R + quad * 4 + c16;
            out[outc + gr] = C + cb;
            A0 += ab0; A1 += ab1;
            float m = fmaxf(A0, A1);
            float e0 = __expf(A0 - m), e1 = __expf(A1 - m);
            float inv = 1.f / (e0 + e1);
            float2 pv; pv.x = e0 * inv; pv.y = e1 * inv;
            opi[gr] = pv;
        }
        bt = nbt;
    }
}

extern "C" void kernel_launch(void* const* d_in, const int* in_sizes, int n_in,
                              void* d_out, int out_size, void* d_ws, size_t ws_size,
                              hipStream_t stream) {
    const float* s        = (const float*)d_in[0];
    const float* h        = (const float*)d_in[1];
    const float* w_ih     = (const float*)d_in[2];
    const float* w_hh     = (const float*)d_in[3];
    const float* b_ih     = (const float*)d_in[4];
    const float* b_hh     = (const float*)d_in[5];
    const float* actor_w  = (const float*)d_in[6];
    const float* actor_b  = (const float*)d_in[7];
    const float* critic_w = (const float*)d_in[8];
    const float* critic_b = (const float*)d_in[9];
    float* out = (float*)d_out;

    int Btot = in_sizes[1] / 50;          // 262144
    int nTiles = Btot / 256;              // 1024 (exact)
    int grid = nTiles < 512 ? nTiles : 512;

    gru_fused<<<grid, BDIM, 0, stream>>>(s, h, w_ih, w_hh, b_ih, b_hh,
                                         actor_w, actor_b, critic_w, critic_b,
                                         out, Btot, nTiles);
}

// Round 2
// 143.057 us; speedup vs baseline: 1.4613x; 1.4613x over previous
//
#include <hip/hip_runtime.h>
#include <hip/hip_bf16.h>

// GRUCell (B=262144, IN=2, H=50) + critic + actor-softmax.
// Inputs fp32, outputs fp32: d_out = h_new[B,50] | c[B,1] | pi[B,2].
// Extended-K MFMA: x[64]=[h(50),s(2),1,0...], W[64]=[w_hh,w_ih,bias,0...].
// R9 = R8 with __launch_bounds__(1024, 8) -> (1024, 4).
// R8's (1024,8) capped the allocator at 64 VGPRs; it compiled to 32 VGPRs
// + scratch spills (FETCH 27->147MB, WRITE 55->220MB) and regressed 2.5x.
// (1024,4) restores the cap (128) under which this body used 60 VGPRs in
// R7; 60 <= 64 still permits 8 waves/SIMD, so the 32-wave/CU occupancy
// ceiling from the 16-wave block (61440B LDS -> 2 blocks/CU) is kept.
// Kernel remains barrier-free after init: each wave owns a private
// 16-row band of the 256-row block tile.

#define BDIM 1024

typedef __bf16 bf16x8 __attribute__((ext_vector_type(8)));
typedef float f32x4 __attribute__((ext_vector_type(4)));
typedef unsigned __attribute__((may_alias)) u32a;
typedef unsigned short __attribute__((may_alias)) u16a;

__device__ __forceinline__ float bf2f(unsigned short u) {
    union { unsigned u; float f; } x; x.u = ((unsigned)u) << 16; return x.f;
}
__device__ __forceinline__ unsigned short f2bf(float f) {   // init path only
    union { float f; unsigned u; } x; x.f = f;
    unsigned r = x.u + 0x7fffu + ((x.u >> 16) & 1u);
    return (unsigned short)(r >> 16);
}
__device__ __forceinline__ unsigned packbf(float a, float b) {  // v_cvt_pk_bf16_f32
    union { __hip_bfloat162 h; unsigned u; } c;
    c.h = __float22bfloat162_rn(make_float2(a, b));
    return c.u;
}
__device__ __forceinline__ bf16x8 ldsfrag(const unsigned short* p) {
    bf16x8 v; __builtin_memcpy(&v, p, 16); return v;   // alias-safe b128 read
}

__global__ __launch_bounds__(BDIM, 4) void gru_fused(
    const float* __restrict__ s,
    const float* __restrict__ h,
    const float* __restrict__ w_ih,
    const float* __restrict__ w_hh,
    const float* __restrict__ b_ih,
    const float* __restrict__ b_hh,
    const float* __restrict__ actor_w,
    const float* __restrict__ actor_b,
    const float* __restrict__ critic_w,
    const float* __restrict__ critic_b,
    float* __restrict__ out,
    int Btot, int nTiles)
{
    // bf16 x-tile: 256 rows x 72 shorts (144B stride); shorts 0..49 h, 50..51 s,
    // 52 = 1.0, 53..63 = 0 (constants written once at init), 64..71 pad.
    __shared__ __align__(16) unsigned short xlds[256 * 72];
    // weight B-fragments: [g(3)][t(4)][ks(2)][lane(64)][8 bf16] — block-shared
    __shared__ __align__(16) unsigned short wlds[1536 * 8];

    const int tid  = threadIdx.x;
    const int wave = tid >> 6;           // 0..15
    const int lane = tid & 63;
    const int c16  = lane & 15;
    const int quad = lane >> 4;
    const int R    = wave * 16;          // this wave's private 16-row band

    u32a* xlds32 = (u32a*)xlds;

    // ---- init: constant zone of xlds (one pass, race-free) ----
    for (int i = tid; i < 256 * 36; i += BDIM)
        xlds32[i] = ((i % 36) == 26) ? 0x00003f80u : 0u;   // k=52 -> 1.0 bf16

    // ---- init: swizzled bf16 weight fragments into wlds ----
    for (int e = tid; e < 1536; e += BDIM) {
        int ln = e & 63;
        int ks = (e >> 6) & 1;
        int t  = (e >> 7) & 3;
        int g  = e >> 9;
        int n  = t * 16 + (ln & 15);
        int kbase = ks * 32 + (ln >> 4) * 8;
        unsigned short vals[8];
        if (n < 50) {
            int r = g * 50 + n;
            #pragma unroll
            for (int i = 0; i < 8; ++i) {
                int k = kbase + i;
                float v = 0.f;
                if (k < 50)       v = w_hh[r * 50 + k];
                else if (k == 50) v = (g < 2) ? w_ih[r * 2 + 0] : 0.f;
                else if (k == 51) v = (g < 2) ? w_ih[r * 2 + 1] : 0.f;
                else if (k == 52) {
                    v = b_hh[r];                 // n-gate: b_hh only
                    if (g < 2) v += b_ih[r];     // r/z: both biases fused
                }
                vals[i] = f2bf(v);
            }
        } else {
            #pragma unroll
            for (int i = 0; i < 8; ++i) vals[i] = 0;
        }
        #pragma unroll
        for (int i = 0; i < 8; ++i) wlds[e * 8 + i] = vals[i];
    }

    // ---- hoisted per-lane constants (loop-invariant global reads) ----
    float wi0[4], wi1[4], bi[4], aw0[4], aw1[4], awc[4];
    #pragma unroll
    for (int t = 0; t < 4; ++t) {
        int j = t * 16 + c16;
        bool ok = (j < 50);
        wi0[t] = ok ? w_ih[(100 + j) * 2 + 0] : 0.f;
        wi1[t] = ok ? w_ih[(100 + j) * 2 + 1] : 0.f;
        bi[t]  = ok ? b_ih[100 + j]           : 0.f;
        aw0[t] = ok ? actor_w[j]              : 0.f;
        aw1[t] = ok ? actor_w[50 + j]         : 0.f;
        awc[t] = ok ? critic_w[j]             : 0.f;
    }
    const float ab0 = actor_b[0], ab1 = actor_b[1], cb = critic_b[0];

    __syncthreads();   // the ONLY barrier: wlds + xlds const zone visible

    const float2* h2 = (const float2*)h;
    const float2* s2 = (const float2*)s;
    const long long outc = (long long)Btot * 50;
    float2* opi = (float2*)(out + (long long)Btot * 51);

    // ---- prefetch first tile (this wave's 16 rows: 400 h-float2 + 16 s) ----
    float2 pf[7];
    int bt = blockIdx.x;
    {
        long long hb = (long long)(bt * 256 + R) * 25;
        #pragma unroll
        for (int j = 0; j < 6; ++j) pf[j] = h2[hb + lane + j * 64];
        if (lane < 16)      pf[6] = h2[hb + 384 + lane];
        else if (lane < 32) pf[6] = s2[bt * 256 + R + lane - 16];
    }

    while (bt < nTiles) {
        const int rowbase = bt * 256;

        // ---- stage own band: regs -> LDS (alias-safe u32a writes) ----
        #pragma unroll
        for (int j = 0; j < 6; ++j) {
            int d = lane + j * 64;
            int r = d / 25, dk = d - r * 25;
            xlds32[(R + r) * 36 + dk] = packbf(pf[j].x, pf[j].y);
        }
        if (lane < 16)
            xlds32[(R + 15) * 36 + 9 + lane] = packbf(pf[6].x, pf[6].y);
        else if (lane < 32)
            xlds32[(R + lane - 16) * 36 + 25] = packbf(pf[6].x, pf[6].y);

        // compiler fence: staging writes ordered before all following reads
        asm volatile("" ::: "memory");

        // ---- issue next tile's loads (latency hidden by compute) ----
        const int nbt = bt + gridDim.x;
        {
            int pb = (nbt < nTiles) ? nbt : bt;
            long long hb = (long long)(pb * 256 + R) * 25;
            #pragma unroll
            for (int j = 0; j < 6; ++j) pf[j] = h2[hb + lane + j * 64];
            if (lane < 16)      pf[6] = h2[hb + 384 + lane];
            else if (lane < 32) pf[6] = s2[pb * 256 + R + lane - 16];
        }

        // ---- s rows for gate math (L2-hot, 16-lane broadcast) ----
        float2 srow[4];
        #pragma unroll
        for (int reg = 0; reg < 4; ++reg)
            srow[reg] = s2[rowbase + R + quad * 4 + reg];

        // ---- A fragments (own band, alias-safe reads) ----
        const unsigned short* arow = &xlds[(R + c16) * 72 + quad * 8];
        bf16x8 a0 = ldsfrag(arow);        // k 0..31
        bf16x8 a1 = ldsfrag(arow + 32);   // k 32..63

        // ---- per-t: 6 MFMAs then gate math ----
        float hn_r[4][4];
        #pragma unroll
        for (int t = 0; t < 4; ++t) {
            f32x4 ar = {0.f,0.f,0.f,0.f}, az = ar, an = ar;
            const int tb = (t * 128 + lane) * 8;   // shorts; ks +512, g +4096
            bf16x8 br0 = ldsfrag(&wlds[tb]);
            bf16x8 br1 = ldsfrag(&wlds[tb + 512]);
            bf16x8 bz0 = ldsfrag(&wlds[tb + 4096]);
            bf16x8 bz1 = ldsfrag(&wlds[tb + 4608]);
            bf16x8 bn0 = ldsfrag(&wlds[tb + 8192]);
            bf16x8 bn1 = ldsfrag(&wlds[tb + 8704]);
            ar = __builtin_amdgcn_mfma_f32_16x16x32_bf16(a0, br0, ar, 0, 0, 0);
            ar = __builtin_amdgcn_mfma_f32_16x16x32_bf16(a1, br1, ar, 0, 0, 0);
            az = __builtin_amdgcn_mfma_f32_16x16x32_bf16(a0, bz0, az, 0, 0, 0);
            az = __builtin_amdgcn_mfma_f32_16x16x32_bf16(a1, bz1, az, 0, 0, 0);
            an = __builtin_amdgcn_mfma_f32_16x16x32_bf16(a0, bn0, an, 0, 0, 0);
            an = __builtin_amdgcn_mfma_f32_16x16x32_bf16(a1, bn1, an, 0, 0, 0);

            int j = t * 16 + c16;
            #pragma unroll
            for (int reg = 0; reg < 4; ++reg) {
                int lr = R + quad * 4 + reg;       // C/D: row = quad*4+reg
                float inn = fmaf(srow[reg].y, wi1[t],
                            fmaf(srow[reg].x, wi0[t], bi[t]));
                float rg = __builtin_amdgcn_rcpf(1.f + __expf(-ar[reg]));
                float zg = __builtin_amdgcn_rcpf(1.f + __expf(-az[reg]));
                float x = inn + rg * an[reg];
                x = fminf(fmaxf(x, -20.f), 20.f);
                float e2 = __expf(2.f * x);
                float ng = (e2 - 1.f) * __builtin_amdgcn_rcpf(e2 + 1.f);
                float hv = bf2f(((const u16a*)xlds)[lr * 72 + j]);
                float hnew = (1.f - zg) * ng + zg * hv;
                bool ok = (j < 50);
                hn_r[reg][t] = ok ? hnew : 0.f;
                if (ok) out[(long long)(rowbase + lr) * 50 + j] = hnew;
            }
        }

        // ---- heads from registers: 16-lane shfl_xor butterfly per row ----
        float sum0[4], sum1[4], sumc[4];
        #pragma unroll
        for (int reg = 0; reg < 4; ++reg) {
            float p0 = 0.f, p1 = 0.f, pc = 0.f;
            #pragma unroll
            for (int t = 0; t < 4; ++t) {
                p0 = fmaf(hn_r[reg][t], aw0[t], p0);
                p1 = fmaf(hn_r[reg][t], aw1[t], p1);
                pc = fmaf(hn_r[reg][t], awc[t], pc);
            }
            #pragma unroll
            for (int m = 1; m < 16; m <<= 1) {
                p0 += __shfl_xor(p0, m);
                p1 += __shfl_xor(p1, m);
                pc += __shfl_xor(pc, m);
            }
            sum0[reg] = p0; sum1[reg] = p1; sumc[reg] = pc;
        }
        if (c16 < 4) {   // lane c16==reg writes row quad*4+c16
            float A0 = (c16 == 0) ? sum0[0] : (c16 == 1) ? sum0[1]
                     : (c16 == 2) ? sum0[2] : sum0[3];
            float A1 = (c16 == 0) ? sum1[0] : (c16 == 1) ? sum1[1]
                     : (c16 == 2) ? sum1[2] : sum1[3];
            float C  = (c16 == 0) ? sumc[0] : (c16 == 1) ? sumc[1]
                     : (c16 == 2) ? sumc[2] : sumc[3];
            int gr = rowbase + R + quad * 4 + c16;
            out[outc + gr] = C + cb;
            A0 += ab0; A1 += ab1;
            float m = fmaxf(A0, A1);
            float e0 = __expf(A0 - m), e1 = __expf(A1 - m);
            float inv = 1.f / (e0 + e1);
            float2 pv; pv.x = e0 * inv; pv.y = e1 * inv;
            opi[gr] = pv;
        }
        bt = nbt;
    }
}

extern "C" void kernel_launch(void* const* d_in, const int* in_sizes, int n_in,
                              void* d_out, int out_size, void* d_ws, size_t ws_size,
                              hipStream_t stream) {
    const float* s        = (const float*)d_in[0];
    const float* h        = (const float*)d_in[1];
    const float* w_ih     = (const float*)d_in[2];
    const float* w_hh     = (const float*)d_in[3];
    const float* b_ih     = (const float*)d_in[4];
    const float* b_hh     = (const float*)d_in[5];
    const float* actor_w  = (const float*)d_in[6];
    const float* actor_b  = (const float*)d_in[7];
    const float* critic_w = (const float*)d_in[8];
    const float* critic_b = (const float*)d_in[9];
    float* out = (float*)d_out;

    int Btot = in_sizes[1] / 50;          // 262144
    int nTiles = Btot / 256;              // 1024 (exact)
    int grid = nTiles < 512 ? nTiles : 512;

    gru_fused<<<grid, BDIM, 0, stream>>>(s, h, w_ih, w_hh, b_ih, b_hh,
                                         actor_w, actor_b, critic_w, critic_b,
                                         out, Btot, nTiles);
}

// Round 3
// 142.396 us; speedup vs baseline: 1.4681x; 1.0046x over previous
//
#include <hip/hip_runtime.h>
#include <hip/hip_bf16.h>

// GRUCell (B=262144, IN=2, H=50) + critic + actor-softmax.
// Inputs fp32, outputs fp32: d_out = h_new[B,50] | c[B,1] | pi[B,2].
// Extended-K MFMA: x[64]=[h(50),s(2),1,0...], W[64]=[w_hh,w_ih,bias,0...].
// R10 = R9 with the head-reduction __shfl_xor butterfly (48 ds_bpermute
// per wave-tile = ~576 LDS-pipe cycles + serial LDS latency) replaced by
// DPP row_ror rotate-reduce on the VALU pipe. Theory: the per-CU LDS unit
// is the saturated pipe (~28us/CU total; bpermutes are half of it), which
// is why R7(16-wave cap) == R9(32-wave cap) == 48us. DPP reduction cuts
// per-CU LDS time to ~13us and shortens the critical path.
// Kernel remains barrier-free after init: each wave owns a private
// 16-row band of the 256-row block tile.

#define BDIM 1024

typedef __bf16 bf16x8 __attribute__((ext_vector_type(8)));
typedef float f32x4 __attribute__((ext_vector_type(4)));
typedef unsigned __attribute__((may_alias)) u32a;
typedef unsigned short __attribute__((may_alias)) u16a;

__device__ __forceinline__ float bf2f(unsigned short u) {
    union { unsigned u; float f; } x; x.u = ((unsigned)u) << 16; return x.f;
}
__device__ __forceinline__ unsigned short f2bf(float f) {   // init path only
    union { float f; unsigned u; } x; x.f = f;
    unsigned r = x.u + 0x7fffu + ((x.u >> 16) & 1u);
    return (unsigned short)(r >> 16);
}
__device__ __forceinline__ unsigned packbf(float a, float b) {  // v_cvt_pk_bf16_f32
    union { __hip_bfloat162 h; unsigned u; } c;
    c.h = __float22bfloat162_rn(make_float2(a, b));
    return c.u;
}
__device__ __forceinline__ bf16x8 ldsfrag(const unsigned short* p) {
    bf16x8 v; __builtin_memcpy(&v, p, 16); return v;   // alias-safe b128 read
}

// DPP rotate-add within each 16-lane row: VALU pipe, no LDS.
// CTRL: 0x121=row_ror:1, 0x122=ror:2, 0x124=ror:4, 0x128=ror:8.
template <int CTRL>
__device__ __forceinline__ float dpp_add(float v) {
    int s = __builtin_bit_cast(int, v);
    int r = __builtin_amdgcn_update_dpp(s, s, CTRL, 0xf, 0xf, false);
    return v + __builtin_bit_cast(float, r);
}
__device__ __forceinline__ float row16_sum(float v) {
    v = dpp_add<0x128>(v);   // + ror 8
    v = dpp_add<0x124>(v);   // + ror 4
    v = dpp_add<0x122>(v);   // + ror 2
    v = dpp_add<0x121>(v);   // + ror 1 -> every lane has full 16-lane sum
    return v;
}

__global__ __launch_bounds__(BDIM, 4) void gru_fused(
    const float* __restrict__ s,
    const float* __restrict__ h,
    const float* __restrict__ w_ih,
    const float* __restrict__ w_hh,
    const float* __restrict__ b_ih,
    const float* __restrict__ b_hh,
    const float* __restrict__ actor_w,
    const float* __restrict__ actor_b,
    const float* __restrict__ critic_w,
    const float* __restrict__ critic_b,
    float* __restrict__ out,
    int Btot, int nTiles)
{
    // bf16 x-tile: 256 rows x 72 shorts (144B stride); shorts 0..49 h, 50..51 s,
    // 52 = 1.0, 53..63 = 0 (constants written once at init), 64..71 pad.
    __shared__ __align__(16) unsigned short xlds[256 * 72];
    // weight B-fragments: [g(3)][t(4)][ks(2)][lane(64)][8 bf16] — block-shared
    __shared__ __align__(16) unsigned short wlds[1536 * 8];

    const int tid  = threadIdx.x;
    const int wave = tid >> 6;           // 0..15
    const int lane = tid & 63;
    const int c16  = lane & 15;
    const int quad = lane >> 4;
    const int R    = wave * 16;          // this wave's private 16-row band

    u32a* xlds32 = (u32a*)xlds;

    // ---- init: constant zone of xlds (one pass, race-free) ----
    for (int i = tid; i < 256 * 36; i += BDIM)
        xlds32[i] = ((i % 36) == 26) ? 0x00003f80u : 0u;   // k=52 -> 1.0 bf16

    // ---- init: swizzled bf16 weight fragments into wlds ----
    for (int e = tid; e < 1536; e += BDIM) {
        int ln = e & 63;
        int ks = (e >> 6) & 1;
        int t  = (e >> 7) & 3;
        int g  = e >> 9;
        int n  = t * 16 + (ln & 15);
        int kbase = ks * 32 + (ln >> 4) * 8;
        unsigned short vals[8];
        if (n < 50) {
            int r = g * 50 + n;
            #pragma unroll
            for (int i = 0; i < 8; ++i) {
                int k = kbase + i;
                float v = 0.f;
                if (k < 50)       v = w_hh[r * 50 + k];
                else if (k == 50) v = (g < 2) ? w_ih[r * 2 + 0] : 0.f;
                else if (k == 51) v = (g < 2) ? w_ih[r * 2 + 1] : 0.f;
                else if (k == 52) {
                    v = b_hh[r];                 // n-gate: b_hh only
                    if (g < 2) v += b_ih[r];     // r/z: both biases fused
                }
                vals[i] = f2bf(v);
            }
        } else {
            #pragma unroll
            for (int i = 0; i < 8; ++i) vals[i] = 0;
        }
        #pragma unroll
        for (int i = 0; i < 8; ++i) wlds[e * 8 + i] = vals[i];
    }

    // ---- hoisted per-lane constants (loop-invariant global reads) ----
    float wi0[4], wi1[4], bi[4], aw0[4], aw1[4], awc[4];
    #pragma unroll
    for (int t = 0; t < 4; ++t) {
        int j = t * 16 + c16;
        bool ok = (j < 50);
        wi0[t] = ok ? w_ih[(100 + j) * 2 + 0] : 0.f;
        wi1[t] = ok ? w_ih[(100 + j) * 2 + 1] : 0.f;
        bi[t]  = ok ? b_ih[100 + j]           : 0.f;
        aw0[t] = ok ? actor_w[j]              : 0.f;
        aw1[t] = ok ? actor_w[50 + j]         : 0.f;
        awc[t] = ok ? critic_w[j]             : 0.f;
    }
    const float ab0 = actor_b[0], ab1 = actor_b[1], cb = critic_b[0];

    __syncthreads();   // the ONLY barrier: wlds + xlds const zone visible

    const float2* h2 = (const float2*)h;
    const float2* s2 = (const float2*)s;
    const long long outc = (long long)Btot * 50;
    float2* opi = (float2*)(out + (long long)Btot * 51);

    // ---- prefetch first tile (this wave's 16 rows: 400 h-float2 + 16 s) ----
    float2 pf[7];
    int bt = blockIdx.x;
    {
        long long hb = (long long)(bt * 256 + R) * 25;
        #pragma unroll
        for (int j = 0; j < 6; ++j) pf[j] = h2[hb + lane + j * 64];
        if (lane < 16)      pf[6] = h2[hb + 384 + lane];
        else if (lane < 32) pf[6] = s2[bt * 256 + R + lane - 16];
    }

    while (bt < nTiles) {
        const int rowbase = bt * 256;

        // ---- stage own band: regs -> LDS (alias-safe u32a writes) ----
        #pragma unroll
        for (int j = 0; j < 6; ++j) {
            int d = lane + j * 64;
            int r = d / 25, dk = d - r * 25;
            xlds32[(R + r) * 36 + dk] = packbf(pf[j].x, pf[j].y);
        }
        if (lane < 16)
            xlds32[(R + 15) * 36 + 9 + lane] = packbf(pf[6].x, pf[6].y);
        else if (lane < 32)
            xlds32[(R + lane - 16) * 36 + 25] = packbf(pf[6].x, pf[6].y);

        // compiler fence: staging writes ordered before all following reads
        asm volatile("" ::: "memory");

        // ---- issue next tile's loads (latency hidden by compute) ----
        const int nbt = bt + gridDim.x;
        {
            int pb = (nbt < nTiles) ? nbt : bt;
            long long hb = (long long)(pb * 256 + R) * 25;
            #pragma unroll
            for (int j = 0; j < 6; ++j) pf[j] = h2[hb + lane + j * 64];
            if (lane < 16)      pf[6] = h2[hb + 384 + lane];
            else if (lane < 32) pf[6] = s2[pb * 256 + R + lane - 16];
        }

        // ---- s rows for gate math (L2-hot, 16-lane broadcast) ----
        float2 srow[4];
        #pragma unroll
        for (int reg = 0; reg < 4; ++reg)
            srow[reg] = s2[rowbase + R + quad * 4 + reg];

        // ---- A fragments (own band, alias-safe reads) ----
        const unsigned short* arow = &xlds[(R + c16) * 72 + quad * 8];
        bf16x8 a0 = ldsfrag(arow);        // k 0..31
        bf16x8 a1 = ldsfrag(arow + 32);   // k 32..63

        // ---- per-t: 6 MFMAs then gate math ----
        float hn_r[4][4];
        #pragma unroll
        for (int t = 0; t < 4; ++t) {
            f32x4 ar = {0.f,0.f,0.f,0.f}, az = ar, an = ar;
            const int tb = (t * 128 + lane) * 8;   // shorts; ks +512, g +4096
            bf16x8 br0 = ldsfrag(&wlds[tb]);
            bf16x8 br1 = ldsfrag(&wlds[tb + 512]);
            bf16x8 bz0 = ldsfrag(&wlds[tb + 4096]);
            bf16x8 bz1 = ldsfrag(&wlds[tb + 4608]);
            bf16x8 bn0 = ldsfrag(&wlds[tb + 8192]);
            bf16x8 bn1 = ldsfrag(&wlds[tb + 8704]);
            ar = __builtin_amdgcn_mfma_f32_16x16x32_bf16(a0, br0, ar, 0, 0, 0);
            ar = __builtin_amdgcn_mfma_f32_16x16x32_bf16(a1, br1, ar, 0, 0, 0);
            az = __builtin_amdgcn_mfma_f32_16x16x32_bf16(a0, bz0, az, 0, 0, 0);
            az = __builtin_amdgcn_mfma_f32_16x16x32_bf16(a1, bz1, az, 0, 0, 0);
            an = __builtin_amdgcn_mfma_f32_16x16x32_bf16(a0, bn0, an, 0, 0, 0);
            an = __builtin_amdgcn_mfma_f32_16x16x32_bf16(a1, bn1, an, 0, 0, 0);

            int j = t * 16 + c16;
            #pragma unroll
            for (int reg = 0; reg < 4; ++reg) {
                int lr = R + quad * 4 + reg;       // C/D: row = quad*4+reg
                float inn = fmaf(srow[reg].y, wi1[t],
                            fmaf(srow[reg].x, wi0[t], bi[t]));
                float rg = __builtin_amdgcn_rcpf(1.f + __expf(-ar[reg]));
                float zg = __builtin_amdgcn_rcpf(1.f + __expf(-az[reg]));
                float x = inn + rg * an[reg];
                x = fminf(fmaxf(x, -20.f), 20.f);
                float e2 = __expf(2.f * x);
                float ng = (e2 - 1.f) * __builtin_amdgcn_rcpf(e2 + 1.f);
                float hv = bf2f(((const u16a*)xlds)[lr * 72 + j]);
                float hnew = (1.f - zg) * ng + zg * hv;
                bool ok = (j < 50);
                hn_r[reg][t] = ok ? hnew : 0.f;
                if (ok) out[(long long)(rowbase + lr) * 50 + j] = hnew;
            }
        }

        // ---- heads from registers: DPP row_ror rotate-reduce (VALU pipe,
        // no LDS). Every lane ends with the full 16-lane sum, same
        // semantics as the old shfl_xor butterfly. ----
        float sum0[4], sum1[4], sumc[4];
        #pragma unroll
        for (int reg = 0; reg < 4; ++reg) {
            float p0 = 0.f, p1 = 0.f, pc = 0.f;
            #pragma unroll
            for (int t = 0; t < 4; ++t) {
                p0 = fmaf(hn_r[reg][t], aw0[t], p0);
                p1 = fmaf(hn_r[reg][t], aw1[t], p1);
                pc = fmaf(hn_r[reg][t], awc[t], pc);
            }
            sum0[reg] = row16_sum(p0);
            sum1[reg] = row16_sum(p1);
            sumc[reg] = row16_sum(pc);
        }
        if (c16 < 4) {   // lane c16==reg writes row quad*4+c16
            float A0 = (c16 == 0) ? sum0[0] : (c16 == 1) ? sum0[1]
                     : (c16 == 2) ? sum0[2] : sum0[3];
            float A1 = (c16 == 0) ? sum1[0] : (c16 == 1) ? sum1[1]
                     : (c16 == 2) ? sum1[2] : sum1[3];
            float C  = (c16 == 0) ? sumc[0] : (c16 == 1) ? sumc[1]
                     : (c16 == 2) ? sumc[2] : sumc[3];
            int gr = rowbase + R + quad * 4 + c16;
            out[outc + gr] = C + cb;
            A0 += ab0; A1 += ab1;
            float m = fmaxf(A0, A1);
            float e0 = __expf(A0 - m), e1 = __expf(A1 - m);
            float inv = 1.f / (e0 + e1);
            float2 pv; pv.x = e0 * inv; pv.y = e1 * inv;
            opi[gr] = pv;
        }
        bt = nbt;
    }
}

extern "C" void kernel_launch(void* const* d_in, const int* in_sizes, int n_in,
                              void* d_out, int out_size, void* d_ws, size_t ws_size,
                              hipStream_t stream) {
    const float* s        = (const float*)d_in[0];
    const float* h        = (const float*)d_in[1];
    const float* w_ih     = (const float*)d_in[2];
    const float* w_hh     = (const float*)d_in[3];
    const float* b_ih     = (const float*)d_in[4];
    const float* b_hh     = (const float*)d_in[5];
    const float* actor_w  = (const float*)d_in[6];
    const float* actor_b  = (const float*)d_in[7];
    const float* critic_w = (const float*)d_in[8];
    const float* critic_b = (const float*)d_in[9];
    float* out = (float*)d_out;

    int Btot = in_sizes[1] / 50;          // 262144
    int nTiles = Btot / 256;              // 1024 (exact)
    int grid = nTiles < 512 ? nTiles : 512;

    gru_fused<<<grid, BDIM, 0, stream>>>(s, h, w_ih, w_hh, b_ih, b_hh,
                                         actor_w, actor_b, critic_w, critic_b,
                                         out, Btot, nTiles);
}